// Round 8
// baseline (1001.875 us; speedup 1.0000x reference)
//
#include <hip/hip_runtime.h>
#include <math.h>

// SGC: out = log_softmax((A_hat^2 x) W + b), A_hat = D^-1/2 (A+I) D^-1/2
// (A^2 X) W == A^2 (X W): propagate in 40-dim class space.
// Z buffers bf16, 128B-padded rows; MFMA split-bf16 gemm.
// Round-16: prop pull -> PUSH. Three rounds of pull-side tuning (teams,
// padding, 8-deep MLP) each under-delivered ~3x -> per-node serial gather
// is structurally exhausted (10 lanes/node = too little TLP). New prop2_k:
// one block per 256-node bucket; 40-class node accumulators in 42KB LDS
// (stride 41, conflict-free); block STREAMS its ~4096 bucket edges from
// tmp (already bucket-partitioned by part_k): 5 lanes/edge gather one
// uint4 of the src Z row and ds_add_f32 8 floats into LDS. Every edge
// independent -> no serial chain, ~200 gathers in flight/block, coalesced
// writes. CSR infrastructure dies: csr_k -> deg_k (count-only, no col
// scatter); rowptr/col eliminated; tmp/T now persist through both hops
// (moved out of the Z0 overlay). Launches stay 7. fp32 add-order changes
// only -> absmax stays bf16-dominated (0.015625).

#define FDIM 128
#define CDIM 40
#define BKT_SHIFT 8
#define NB   512   // bucket slots (>= ceil(N/256))
#define NBLK 512   // edge-partition blocks
#define ZSTR 8     // Z row stride in uint4 (128 B; 5 used, 3 pad)
#define ASTR 41    // LDS accumulator row stride (floats); 41 coprime 32

typedef __attribute__((ext_vector_type(4))) float floatx4;
typedef __attribute__((ext_vector_type(8))) short bshort8;

// ---------- bf16 helpers (RTNE pack; finite inputs) ----------
__device__ __forceinline__ unsigned int bf16rn(float f) {
    unsigned int u = __float_as_uint(f);
    return (u + 0x7fffu + ((u >> 16) & 1u)) >> 16;
}
__device__ __forceinline__ unsigned int pack2(float lo, float hi) {
    unsigned int a = bf16rn(lo);
    unsigned int b = __float_as_uint(hi);
    b = (b + 0x7fffu + ((b >> 16) & 1u)) & 0xffff0000u;
    return a | b;
}
__device__ __forceinline__ void unpack8(uint4 u, float* a) {
    a[0] = __uint_as_float(u.x << 16);
    a[1] = __uint_as_float(u.x & 0xffff0000u);
    a[2] = __uint_as_float(u.y << 16);
    a[3] = __uint_as_float(u.y & 0xffff0000u);
    a[4] = __uint_as_float(u.z << 16);
    a[5] = __uint_as_float(u.z & 0xffff0000u);
    a[6] = __uint_as_float(u.w << 16);
    a[7] = __uint_as_float(u.w & 0xffff0000u);
}
__device__ __forceinline__ void atomAdd8(float* p, uint4 u) {
    float a[8];
    unpack8(u, a);
    #pragma unroll
    for (int k = 0; k < 8; ++k) atomicAdd(p + k, a[k]);
}

// ---- pass 1: per-block histogram over dst buckets (LDS, no global atomics).
// Block NBLK rides along as the W fragment prep (split-bf16, MFMA B order).
__global__ void hist_k(const int* __restrict__ dst, int* __restrict__ G,
                       int E, int EB, const float* __restrict__ W,
                       uint4* __restrict__ WF) {
    int t = threadIdx.x;
    if (blockIdx.x == NBLK) {
        // wprep: B frag for mfma_f32_16x16x32_bf16: lane l holds
        // B[k = 8*(l>>4)+j][n = l&15]; g = nt*4+ch; hi at WF[g*64+l],
        // lo at WF[768+g*64+l]. k_global = ch*32+8*(l>>4)+j.
        for (int s = t; s < 768; s += 256) {
            int l = s & 63;
            int g = s >> 6;
            int nt = g >> 2;
            int ch = g & 3;
            int c = nt * 16 + (l & 15);
            int kb = ch * 32 + ((l >> 4) << 3);
            unsigned int hw[4], lw[4];
            #pragma unroll
            for (int jw = 0; jw < 4; ++jw) {
                unsigned int hs[2], ls[2];
                #pragma unroll
                for (int e = 0; e < 2; ++e) {
                    int j = jw * 2 + e;
                    float w = (c < CDIM) ? W[(kb + j) * CDIM + c] : 0.f;
                    unsigned int u = __float_as_uint(w);
                    float wh = __uint_as_float(u & 0xffff0000u);
                    float wr = w - wh;
                    hs[e] = u >> 16;
                    ls[e] = __float_as_uint(wr) >> 16;
                }
                hw[jw] = hs[0] | (hs[1] << 16);
                lw[jw] = ls[0] | (ls[1] << 16);
            }
            WF[g * 64 + l] = make_uint4(hw[0], hw[1], hw[2], hw[3]);
            WF[768 + g * 64 + l] = make_uint4(lw[0], lw[1], lw[2], lw[3]);
        }
        return;
    }
    __shared__ int h[NB];
    for (int i = t; i < NB; i += 256) h[i] = 0;
    __syncthreads();
    int s = blockIdx.x * EB;
    int e = min(s + EB, E);
    for (int i = s + t; i < e; i += 256)
        atomicAdd(&h[dst[i] >> BKT_SHIFT], 1);
    __syncthreads();
    for (int i = t; i < NB; i += 256) G[blockIdx.x * NB + i] = h[i];
}

// ---- pass 2: per-bucket exclusive scan over blocks (in-place on G); totals->T
__global__ void colscan_k(int* __restrict__ G, int* __restrict__ T) {
    __shared__ int lds[256];
    int j = blockIdx.x;
    int t = threadIdx.x;
    int v0 = G[(2 * t) * NB + j];
    int v1 = G[(2 * t + 1) * NB + j];
    int s = v0 + v1;
    lds[t] = s;
    __syncthreads();
    for (int off = 1; off < 256; off <<= 1) {
        int a = (t >= off) ? lds[t - off] : 0;
        __syncthreads();
        lds[t] += a;
        __syncthreads();
    }
    int excl = lds[t] - s;
    G[(2 * t) * NB + j] = excl;
    G[(2 * t + 1) * NB + j] = excl + v0;
    if (t == 255) T[j] = lds[255];
}

// ---- inline exclusive scan of T[0..NB) into bsl[0..NB] (bsl[NB]=total).
__device__ __forceinline__ void scanT(const int* __restrict__ T, int* bsl,
                                      int* lds, int t) {
    int v0 = T[2 * t];
    int v1 = T[2 * t + 1];
    int s = v0 + v1;
    lds[t] = s;
    __syncthreads();
    for (int off = 1; off < 256; off <<= 1) {
        int a = (t >= off) ? lds[t - off] : 0;
        __syncthreads();
        lds[t] += a;
        __syncthreads();
    }
    int excl = lds[t] - s;
    bsl[2 * t] = excl;
    bsl[2 * t + 1] = excl + v0;
    if (t == 255) bsl[NB] = lds[255];
    __syncthreads();
}

// ---- pass 3: scatter packed edges into bucket-partitioned tmp
// pack: src (24 bits) | dstLocal (8 bits) << 24   [requires N < 2^24]
__global__ void part_k(const int* __restrict__ src, const int* __restrict__ dst,
                       const int* __restrict__ G, const int* __restrict__ T,
                       unsigned int* __restrict__ tmp, int E, int EB) {
    __shared__ int bsl[NB + 1];
    __shared__ int lds[256];
    __shared__ int offs[NB];
    __shared__ int cur[NB];
    int t = threadIdx.x;
    scanT(T, bsl, lds, t);
    for (int i = t; i < NB; i += 256) {
        offs[i] = bsl[i] + G[blockIdx.x * NB + i];
        cur[i] = 0;
    }
    __syncthreads();
    int s = blockIdx.x * EB;
    int e = min(s + EB, E);
    for (int i = s + t; i < e; i += 256) {
        int d = dst[i];
        int j = d >> BKT_SHIFT;
        int r = atomicAdd(&cur[j], 1);
        tmp[offs[j] + r] = (unsigned int)src[i] | ((unsigned int)(d & 255) << 24);
    }
}

// ---- pass 4: one block per bucket: degree count only -> dinv/dsq.
// (CSR col scatter eliminated: push-prop consumes tmp directly.)
__global__ __launch_bounds__(256) void deg_k(const unsigned int* __restrict__ tmp,
                                             const int* __restrict__ T,
                                             float* __restrict__ dinv,
                                             float* __restrict__ dsq, int N) {
    __shared__ int bsl[NB + 1];
    __shared__ int lds[256];
    __shared__ int cnt[256];
    int j = blockIdx.x;
    int t = threadIdx.x;
    cnt[t] = 0;
    scanT(T, bsl, lds, t);   // barriers order cnt zero-init before use
    int s = bsl[j];
    int e = bsl[j + 1];
    for (int i = s + t; i < e; i += 256)
        atomicAdd(&cnt[tmp[i] >> 24], 1);
    __syncthreads();
    int node = (j << BKT_SHIFT) + t;
    if (node < N) {
        float d = (float)(cnt[t] + 1);         // +1 self-loop
        dinv[node] = rsqrtf(d);
        dsq[node] = sqrtf(d);
    }
}

// ---- Z0[node][40] (bf16) = dinv[node] * (x[node] @ W)  -- MFMA.
// Wave = 16 nodes x 40 classes (3 N-tiles of 16). A frag (lane l: row l&15,
// k=8*(l>>4)+j) loads straight from global x (16 rows x 64B contiguous per
// instr). 3 MFMAs per (nt,ch): xh*Wh + xl*Wh + xh*Wl (split-bf16, rel err
// ~2^-15). Epilogue transposes D frags through 13KB LDS into 128B rows.
__device__ __forceinline__ void split8(const float* p, bshort8& hi, bshort8& lo) {
    float4 a = *(const float4*)p;
    float4 b = *(const float4*)(p + 4);
    float f[8] = {a.x, a.y, a.z, a.w, b.x, b.y, b.z, b.w};
    #pragma unroll
    for (int j = 0; j < 8; ++j) {
        unsigned int u = __float_as_uint(f[j]);
        float r = f[j] - __uint_as_float(u & 0xffff0000u);
        hi[j] = (short)(u >> 16);
        lo[j] = (short)(__float_as_uint(r) >> 16);
    }
}

#define EPS 52   // epilogue LDS row stride (floats)

__global__ __launch_bounds__(256) void gemm_k(const float* __restrict__ x,
                                              const uint4* __restrict__ WF,
                                              const float* __restrict__ dinv,
                                              uint4* __restrict__ Zbf, int n) {
    __shared__ float ep[64 * EPS];   // 13.3 KB
    int t = threadIdx.x;
    int wid = t >> 6;
    int l = t & 63;
    int lr = l & 15;
    int lg = l >> 4;
    int base64 = blockIdx.x * 64;
    int mbase = base64 + wid * 16;
    int node_a = mbase + lr;
    bool arow_ok = node_a < n;
    const bshort8* WFv = (const bshort8*)WF;

    floatx4 acc0 = {0.f, 0.f, 0.f, 0.f};
    floatx4 acc1 = {0.f, 0.f, 0.f, 0.f};
    floatx4 acc2 = {0.f, 0.f, 0.f, 0.f};

    #pragma unroll
    for (int ch = 0; ch < 4; ++ch) {
        bshort8 ah, al;
        if (arow_ok) {
            split8(x + (size_t)node_a * FDIM + ch * 32 + lg * 8, ah, al);
        } else {
            #pragma unroll
            for (int j = 0; j < 8; ++j) { ah[j] = 0; al[j] = 0; }
        }
        bshort8 bh0 = WFv[(0 * 4 + ch) * 64 + l];
        bshort8 bl0 = WFv[768 + (0 * 4 + ch) * 64 + l];
        bshort8 bh1 = WFv[(1 * 4 + ch) * 64 + l];
        bshort8 bl1 = WFv[768 + (1 * 4 + ch) * 64 + l];
        bshort8 bh2 = WFv[(2 * 4 + ch) * 64 + l];
        bshort8 bl2 = WFv[768 + (2 * 4 + ch) * 64 + l];
        acc0 = __builtin_amdgcn_mfma_f32_16x16x32_bf16(ah, bh0, acc0, 0, 0, 0);
        acc0 = __builtin_amdgcn_mfma_f32_16x16x32_bf16(al, bh0, acc0, 0, 0, 0);
        acc0 = __builtin_amdgcn_mfma_f32_16x16x32_bf16(ah, bl0, acc0, 0, 0, 0);
        acc1 = __builtin_amdgcn_mfma_f32_16x16x32_bf16(ah, bh1, acc1, 0, 0, 0);
        acc1 = __builtin_amdgcn_mfma_f32_16x16x32_bf16(al, bh1, acc1, 0, 0, 0);
        acc1 = __builtin_amdgcn_mfma_f32_16x16x32_bf16(ah, bl1, acc1, 0, 0, 0);
        acc2 = __builtin_amdgcn_mfma_f32_16x16x32_bf16(ah, bh2, acc2, 0, 0, 0);
        acc2 = __builtin_amdgcn_mfma_f32_16x16x32_bf16(al, bh2, acc2, 0, 0, 0);
        acc2 = __builtin_amdgcn_mfma_f32_16x16x32_bf16(ah, bl2, acc2, 0, 0, 0);
    }

    // epilogue: D lane l reg r -> node mbase + 4*lg + r, class nt*16 + lr.
    int nlb = wid * 16 + 4 * lg;
    #pragma unroll
    for (int r = 0; r < 4; ++r) {
        int nd = mbase + 4 * lg + r;
        float di = (nd < n) ? dinv[nd] : 0.f;
        ep[(nlb + r) * EPS + 0 * 16 + lr] = acc0[r] * di;
        ep[(nlb + r) * EPS + 1 * 16 + lr] = acc1[r] * di;
        ep[(nlb + r) * EPS + 2 * 16 + lr] = acc2[r] * di;
    }
    __syncthreads();
    for (int i = t; i < 320; i += 256) {
        int nl2 = i / 5;
        int cg = i - nl2 * 5;
        int node = base64 + nl2;
        if (node < n) {
            const float* p = &ep[nl2 * EPS + cg * 8];
            float4 v0 = *(const float4*)p;
            float4 v1 = *(const float4*)(p + 4);
            uint4 o;
            o.x = pack2(v0.x, v0.y);
            o.y = pack2(v0.z, v0.w);
            o.z = pack2(v1.x, v1.y);
            o.w = pack2(v1.z, v1.w);
            Zbf[(size_t)node * ZSTR + cg] = o;
        }
    }
}

// ---- one hop, PUSH style: block = one 256-node bucket. 42KB LDS holds
// acc[256][ASTR]; stream bucket edges (5 lanes/edge, 4-deep unroll,
// ~200 gathers in flight), ds_add_f32 into LDS. Epilogue per thread-node:
// + self-loop, x di^2; !FINAL packs bf16 Z row; FINAL computes logits
// (x dsq + bias) and log_softmax, writes fp32.
template <bool FINAL>
__global__ __launch_bounds__(256) void prop2_k(const unsigned int* __restrict__ tmp,
                                               const int* __restrict__ T,
                                               const float* __restrict__ dinv,
                                               const float* __restrict__ dsq,
                                               const float* __restrict__ bias,
                                               const uint4* __restrict__ Zin,
                                               uint4* __restrict__ Zout_bf,
                                               float* __restrict__ out_f32, int n) {
    __shared__ float accf[256 * ASTR];   // 42 KB
    __shared__ int bsl[NB + 1];
    __shared__ int lds[256];
    __shared__ float bsm[CDIM];
    int j = blockIdx.x;
    int t = threadIdx.x;
    if (FINAL && t < CDIM) bsm[t] = bias[t];
    for (int i = t; i < 256 * ASTR; i += 256) accf[i] = 0.f;
    scanT(T, bsl, lds, t);   // internal barriers order the zero-init
    int s = bsl[j];
    int e = bsl[j + 1];
    int el = t / 5;          // 0..50 edge lane-groups (t=255 idle in loop)
    int c8 = t - el * 5;     // 0..4: which uint4 of the Z row
    if (el < 51) {
        int i = s + el;
        for (; i + 153 < e; i += 204) {   // 4 edges in flight per lane
            unsigned int p0 = tmp[i];
            unsigned int p1 = tmp[i + 51];
            unsigned int p2 = tmp[i + 102];
            unsigned int p3 = tmp[i + 153];
            uint4 a0 = Zin[(size_t)(p0 & 0xFFFFFFu) * ZSTR + c8];
            uint4 a1 = Zin[(size_t)(p1 & 0xFFFFFFu) * ZSTR + c8];
            uint4 a2 = Zin[(size_t)(p2 & 0xFFFFFFu) * ZSTR + c8];
            uint4 a3 = Zin[(size_t)(p3 & 0xFFFFFFu) * ZSTR + c8];
            atomAdd8(&accf[(p0 >> 24) * ASTR + c8 * 8], a0);
            atomAdd8(&accf[(p1 >> 24) * ASTR + c8 * 8], a1);
            atomAdd8(&accf[(p2 >> 24) * ASTR + c8 * 8], a2);
            atomAdd8(&accf[(p3 >> 24) * ASTR + c8 * 8], a3);
        }
        for (; i < e; i += 51) {
            unsigned int p = tmp[i];
            uint4 a = Zin[(size_t)(p & 0xFFFFFFu) * ZSTR + c8];
            atomAdd8(&accf[(p >> 24) * ASTR + c8 * 8], a);
        }
    }
    __syncthreads();

    // epilogue: thread t owns node base + t. accf row reads are stride-41
    // (coprime with 32 banks -> conflict-free).
    int node = (j << BKT_SHIFT) + t;
    if (node >= n) return;
    float di = dinv[node];
    float w = di * di;
    const uint4* zr = Zin + (size_t)node * ZSTR;
    float v[CDIM];
    #pragma unroll
    for (int gq = 0; gq < 5; ++gq) {
        float sl[8];
        unpack8(zr[gq], sl);            // self-loop term
        #pragma unroll
        for (int k = 0; k < 8; ++k)
            v[gq * 8 + k] = accf[t * ASTR + gq * 8 + k] + sl[k];
    }
    if (!FINAL) {
        uint4* zo = Zout_bf + (size_t)node * ZSTR;
        #pragma unroll
        for (int gq = 0; gq < 5; ++gq) {
            uint4 o;
            o.x = pack2(v[gq * 8 + 0] * w, v[gq * 8 + 1] * w);
            o.y = pack2(v[gq * 8 + 2] * w, v[gq * 8 + 3] * w);
            o.z = pack2(v[gq * 8 + 4] * w, v[gq * 8 + 5] * w);
            o.w = pack2(v[gq * 8 + 6] * w, v[gq * 8 + 7] * w);
            zo[gq] = o;
        }
        return;
    }
    float ws_ = w * dsq[node];
    float m = -INFINITY;
    #pragma unroll
    for (int c = 0; c < CDIM; ++c) {
        v[c] = v[c] * ws_ + bsm[c];
        m = fmaxf(m, v[c]);
    }
    float sum = 0.f;
    #pragma unroll
    for (int c = 0; c < CDIM; ++c) sum += expf(v[c] - m);
    float ls = m + logf(sum);
    float* p = out_f32 + (size_t)node * CDIM;
    #pragma unroll
    for (int gq = 0; gq < 10; ++gq)
        *(float4*)(p + gq * 4) = make_float4(v[gq * 4 + 0] - ls, v[gq * 4 + 1] - ls,
                                             v[gq * 4 + 2] - ls, v[gq * 4 + 3] - ls);
}

extern "C" void kernel_launch(void* const* d_in, const int* in_sizes, int n_in,
                              void* d_out, int out_size, void* d_ws, size_t ws_size,
                              hipStream_t stream) {
    const float* x = (const float*)d_in[0];
    const float* W = (const float*)d_in[1];
    const float* b = (const float*)d_in[2];
    const int* ei = (const int*)d_in[3];

    int C = in_sizes[2];            // 40
    int F = in_sizes[1] / C;        // 128
    int N = in_sizes[0] / F;        // 100000
    int E = in_sizes[3] / 2;        // 1600000
    const int* src = ei;
    const int* dst = ei + E;

    // workspace: G (1MB, dead after part_k) overlaid by Z0bf (12.8MB).
    // T and tmp PERSIST through both prop hops (push-prop reads them) ->
    // separate regions. col/rowptr eliminated.
    char* ws = (char*)d_ws;
    size_t gbytes = (size_t)NBLK * NB * 4;          // 1 MB
    size_t z0bytes = (size_t)N * ZSTR * 16;         // 12.8 MB
    int* G = (int*)ws;
    uint4* Z0bf = (uint4*)ws;                       // overlays G after part_k
    size_t off = ((z0bytes > gbytes ? z0bytes : gbytes) + 15) & ~(size_t)15;
    int* T = (int*)(ws + off);      off += ((size_t)NB * 4 + 15) & ~(size_t)15;
    unsigned int* tmp = (unsigned int*)(ws + off); off += ((size_t)E * 4 + 15) & ~(size_t)15;
    float* dinv = (float*)(ws + off); off += ((size_t)N * 4 + 15) & ~(size_t)15;
    float* dsq = (float*)(ws + off);  off += ((size_t)N * 4 + 15) & ~(size_t)15;
    uint4* Zb = (uint4*)(ws + off);   off += (z0bytes + 15) & ~(size_t)15;
    uint4* WF = (uint4*)(ws + off);   off += (size_t)2 * 768 * 16;

    int EB = (E + NBLK - 1) / NBLK;
    int NBr = (N + 255) >> BKT_SHIFT;

    hist_k<<<NBLK + 1, 256, 0, stream>>>(dst, G, E, EB, W, WF);
    colscan_k<<<NB, 256, 0, stream>>>(G, T);
    part_k<<<NBLK, 256, 0, stream>>>(src, dst, G, T, tmp, E, EB);
    deg_k<<<NBr, 256, 0, stream>>>(tmp, T, dinv, dsq, N);

    gemm_k<<<(N + 63) / 64, 256, 0, stream>>>(x, WF, dinv, Z0bf, N);

    prop2_k<false><<<NBr, 256, 0, stream>>>(tmp, T, dinv, dsq, b,
                                            Z0bf, Zb, nullptr, N);
    prop2_k<true><<<NBr, 256, 0, stream>>>(tmp, T, dinv, dsq, b,
                                           Zb, nullptr, (float*)d_out, N);
}

// Round 9
// 211.962 us; speedup vs baseline: 4.7267x; 4.7267x over previous
//
#include <hip/hip_runtime.h>
#include <math.h>

// SGC: out = log_softmax((A_hat^2 x) W + b), A_hat = D^-1/2 (A+I) D^-1/2
// (A^2 X) W == A^2 (X W): propagate in 40-dim class space.
// Z buffers bf16, 128B-padded rows; MFMA split-bf16 gemm; 2-team pull prop.
// Round-17: REVERT round-16's push prop (catastrophic: 434us/hop, VALU 1.3%
// -- 64M LDS ds_atomic_add_f32 per hop serialize; LDS float-atomic
// throughput is the wall. Also measured: prop gathers fetch ~81MB/hop from
// HBM -> ~69% L2 miss on the 12.8MB Z buffer). Back to round-15 pull
// structure (212.4us best), plus ONE tweak: software-pipelined col loads
// in prop_k (preload 8 indices, prefetch next-8 between gather issue and
// accumulate) -- removes the col->gather serialization at each iter top.

#define FDIM 128
#define CDIM 40
#define BKT_SHIFT 8
#define NB   512   // bucket slots (>= ceil(N/256))
#define NBLK 512   // edge-partition blocks
#define NPB  25    // nodes per 256-thread prop block (10 lanes/node, 2 teams)
#define ZSTR 8     // Z row stride in uint4 (128 B; 5 used, 3 pad)

typedef __attribute__((ext_vector_type(4))) float floatx4;
typedef __attribute__((ext_vector_type(8))) short bshort8;

// ---------- bf16 helpers (RTNE pack; finite inputs) ----------
__device__ __forceinline__ unsigned int bf16rn(float f) {
    unsigned int u = __float_as_uint(f);
    return (u + 0x7fffu + ((u >> 16) & 1u)) >> 16;
}
__device__ __forceinline__ unsigned int pack2(float lo, float hi) {
    unsigned int a = bf16rn(lo);
    unsigned int b = __float_as_uint(hi);
    b = (b + 0x7fffu + ((b >> 16) & 1u)) & 0xffff0000u;
    return a | b;
}
__device__ __forceinline__ void addu4(uint4 u, float* a) {
    a[0] += __uint_as_float(u.x << 16);
    a[1] += __uint_as_float(u.x & 0xffff0000u);
    a[2] += __uint_as_float(u.y << 16);
    a[3] += __uint_as_float(u.y & 0xffff0000u);
    a[4] += __uint_as_float(u.z << 16);
    a[5] += __uint_as_float(u.z & 0xffff0000u);
    a[6] += __uint_as_float(u.w << 16);
    a[7] += __uint_as_float(u.w & 0xffff0000u);
}

// ---- pass 1: per-block histogram over dst buckets (LDS, no global atomics).
// Block NBLK rides along as the W fragment prep (split-bf16, MFMA B order).
__global__ void hist_k(const int* __restrict__ dst, int* __restrict__ G,
                       int E, int EB, const float* __restrict__ W,
                       uint4* __restrict__ WF) {
    int t = threadIdx.x;
    if (blockIdx.x == NBLK) {
        // wprep: B frag for mfma_f32_16x16x32_bf16: lane l holds
        // B[k = 8*(l>>4)+j][n = l&15]; g = nt*4+ch; hi at WF[g*64+l],
        // lo at WF[768+g*64+l]. k_global = ch*32+8*(l>>4)+j.
        for (int s = t; s < 768; s += 256) {
            int l = s & 63;
            int g = s >> 6;
            int nt = g >> 2;
            int ch = g & 3;
            int c = nt * 16 + (l & 15);
            int kb = ch * 32 + ((l >> 4) << 3);
            unsigned int hw[4], lw[4];
            #pragma unroll
            for (int jw = 0; jw < 4; ++jw) {
                unsigned int hs[2], ls[2];
                #pragma unroll
                for (int e = 0; e < 2; ++e) {
                    int j = jw * 2 + e;
                    float w = (c < CDIM) ? W[(kb + j) * CDIM + c] : 0.f;
                    unsigned int u = __float_as_uint(w);
                    float wh = __uint_as_float(u & 0xffff0000u);
                    float wr = w - wh;
                    hs[e] = u >> 16;
                    ls[e] = __float_as_uint(wr) >> 16;
                }
                hw[jw] = hs[0] | (hs[1] << 16);
                lw[jw] = ls[0] | (ls[1] << 16);
            }
            WF[g * 64 + l] = make_uint4(hw[0], hw[1], hw[2], hw[3]);
            WF[768 + g * 64 + l] = make_uint4(lw[0], lw[1], lw[2], lw[3]);
        }
        return;
    }
    __shared__ int h[NB];
    for (int i = t; i < NB; i += 256) h[i] = 0;
    __syncthreads();
    int s = blockIdx.x * EB;
    int e = min(s + EB, E);
    for (int i = s + t; i < e; i += 256)
        atomicAdd(&h[dst[i] >> BKT_SHIFT], 1);
    __syncthreads();
    for (int i = t; i < NB; i += 256) G[blockIdx.x * NB + i] = h[i];
}

// ---- pass 2: per-bucket exclusive scan over blocks (in-place on G); totals->T
__global__ void colscan_k(int* __restrict__ G, int* __restrict__ T) {
    __shared__ int lds[256];
    int j = blockIdx.x;
    int t = threadIdx.x;
    int v0 = G[(2 * t) * NB + j];
    int v1 = G[(2 * t + 1) * NB + j];
    int s = v0 + v1;
    lds[t] = s;
    __syncthreads();
    for (int off = 1; off < 256; off <<= 1) {
        int a = (t >= off) ? lds[t - off] : 0;
        __syncthreads();
        lds[t] += a;
        __syncthreads();
    }
    int excl = lds[t] - s;
    G[(2 * t) * NB + j] = excl;
    G[(2 * t + 1) * NB + j] = excl + v0;
    if (t == 255) T[j] = lds[255];
}

// ---- inline exclusive scan of T[0..NB) into bsl[0..NB] (bsl[NB]=total).
__device__ __forceinline__ void scanT(const int* __restrict__ T, int* bsl,
                                      int* lds, int t) {
    int v0 = T[2 * t];
    int v1 = T[2 * t + 1];
    int s = v0 + v1;
    lds[t] = s;
    __syncthreads();
    for (int off = 1; off < 256; off <<= 1) {
        int a = (t >= off) ? lds[t - off] : 0;
        __syncthreads();
        lds[t] += a;
        __syncthreads();
    }
    int excl = lds[t] - s;
    bsl[2 * t] = excl;
    bsl[2 * t + 1] = excl + v0;
    if (t == 255) bsl[NB] = lds[255];
    __syncthreads();
}

// ---- pass 3: scatter packed edges into bucket-partitioned tmp
// pack: src (24 bits) | dstLocal (8 bits) << 24   [requires N < 2^24]
__global__ void part_k(const int* __restrict__ src, const int* __restrict__ dst,
                       const int* __restrict__ G, const int* __restrict__ T,
                       unsigned int* __restrict__ tmp, int E, int EB) {
    __shared__ int bsl[NB + 1];
    __shared__ int lds[256];
    __shared__ int offs[NB];
    __shared__ int cur[NB];
    int t = threadIdx.x;
    scanT(T, bsl, lds, t);
    for (int i = t; i < NB; i += 256) {
        offs[i] = bsl[i] + G[blockIdx.x * NB + i];
        cur[i] = 0;
    }
    __syncthreads();
    int s = blockIdx.x * EB;
    int e = min(s + EB, E);
    for (int i = s + t; i < e; i += 256) {
        int d = dst[i];
        int j = d >> BKT_SHIFT;
        int r = atomicAdd(&cur[j], 1);
        tmp[offs[j] + r] = (unsigned int)src[i] | ((unsigned int)(d & 255) << 24);
    }
}

// ---- pass 4: one block per bucket: rowptr/dinv/dsq + CSR col fill (all local)
__global__ void csr_k(const unsigned int* __restrict__ tmp, const int* __restrict__ T,
                      int* __restrict__ rowptr, float* __restrict__ dinv,
                      float* __restrict__ dsq, int* __restrict__ col, int N, int E) {
    __shared__ int bsl[NB + 1];
    __shared__ int lds[256];
    __shared__ int cnt[256];
    __shared__ int ptr[256];
    int j = blockIdx.x;
    int t = threadIdx.x;
    scanT(T, bsl, lds, t);
    int base = j << BKT_SHIFT;
    int s = bsl[j];
    int e = bsl[j + 1];
    cnt[t] = 0;
    __syncthreads();
    for (int i = s + t; i < e; i += 256)
        atomicAdd(&cnt[tmp[i] >> 24], 1);
    __syncthreads();
    int v = cnt[t];
    ptr[t] = v;
    __syncthreads();
    for (int off = 1; off < 256; off <<= 1) {
        int a = (t >= off) ? ptr[t - off] : 0;
        __syncthreads();
        ptr[t] += a;
        __syncthreads();
    }
    int excl = ptr[t] - v;
    int node = base + t;
    if (node < N) {
        rowptr[node] = s + excl;
        float d = (float)(v + 1);              // +1 self-loop
        dinv[node] = rsqrtf(d);
        dsq[node] = sqrtf(d);
    }
    if (j == 0 && t == 0) rowptr[N] = E;
    cnt[t] = excl;  // cursor
    __syncthreads();
    for (int i = s + t; i < e; i += 256) {
        unsigned int p = tmp[i];
        int loc = p >> 24;
        int r = atomicAdd(&cnt[loc], 1);
        col[s + r] = (int)(p & 0xFFFFFF);
    }
}

// ---- Z0[node][40] (bf16) = dinv[node] * (x[node] @ W)  -- MFMA.
// Wave = 16 nodes x 40 classes (3 N-tiles of 16). A frag (lane l: row l&15,
// k=8*(l>>4)+j) loads straight from global x (16 rows x 64B contiguous per
// instr). 3 MFMAs per (nt,ch): xh*Wh + xl*Wh + xh*Wl (split-bf16, rel err
// ~2^-15). Epilogue transposes D frags through 13KB LDS into 128B rows.
__device__ __forceinline__ void split8(const float* p, bshort8& hi, bshort8& lo) {
    float4 a = *(const float4*)p;
    float4 b = *(const float4*)(p + 4);
    float f[8] = {a.x, a.y, a.z, a.w, b.x, b.y, b.z, b.w};
    #pragma unroll
    for (int j = 0; j < 8; ++j) {
        unsigned int u = __float_as_uint(f[j]);
        float r = f[j] - __uint_as_float(u & 0xffff0000u);
        hi[j] = (short)(u >> 16);
        lo[j] = (short)(__float_as_uint(r) >> 16);
    }
}

#define EPS 52   // epilogue LDS row stride (floats)

__global__ __launch_bounds__(256) void gemm_k(const float* __restrict__ x,
                                              const uint4* __restrict__ WF,
                                              const float* __restrict__ dinv,
                                              uint4* __restrict__ Zbf, int n) {
    __shared__ float ep[64 * EPS];   // 13.3 KB
    int t = threadIdx.x;
    int wid = t >> 6;
    int l = t & 63;
    int lr = l & 15;
    int lg = l >> 4;
    int base64 = blockIdx.x * 64;
    int mbase = base64 + wid * 16;
    int node_a = mbase + lr;
    bool arow_ok = node_a < n;
    const bshort8* WFv = (const bshort8*)WF;

    floatx4 acc0 = {0.f, 0.f, 0.f, 0.f};
    floatx4 acc1 = {0.f, 0.f, 0.f, 0.f};
    floatx4 acc2 = {0.f, 0.f, 0.f, 0.f};

    #pragma unroll
    for (int ch = 0; ch < 4; ++ch) {
        bshort8 ah, al;
        if (arow_ok) {
            split8(x + (size_t)node_a * FDIM + ch * 32 + lg * 8, ah, al);
        } else {
            #pragma unroll
            for (int j = 0; j < 8; ++j) { ah[j] = 0; al[j] = 0; }
        }
        bshort8 bh0 = WFv[(0 * 4 + ch) * 64 + l];
        bshort8 bl0 = WFv[768 + (0 * 4 + ch) * 64 + l];
        bshort8 bh1 = WFv[(1 * 4 + ch) * 64 + l];
        bshort8 bl1 = WFv[768 + (1 * 4 + ch) * 64 + l];
        bshort8 bh2 = WFv[(2 * 4 + ch) * 64 + l];
        bshort8 bl2 = WFv[768 + (2 * 4 + ch) * 64 + l];
        acc0 = __builtin_amdgcn_mfma_f32_16x16x32_bf16(ah, bh0, acc0, 0, 0, 0);
        acc0 = __builtin_amdgcn_mfma_f32_16x16x32_bf16(al, bh0, acc0, 0, 0, 0);
        acc0 = __builtin_amdgcn_mfma_f32_16x16x32_bf16(ah, bl0, acc0, 0, 0, 0);
        acc1 = __builtin_amdgcn_mfma_f32_16x16x32_bf16(ah, bh1, acc1, 0, 0, 0);
        acc1 = __builtin_amdgcn_mfma_f32_16x16x32_bf16(al, bh1, acc1, 0, 0, 0);
        acc1 = __builtin_amdgcn_mfma_f32_16x16x32_bf16(ah, bl1, acc1, 0, 0, 0);
        acc2 = __builtin_amdgcn_mfma_f32_16x16x32_bf16(ah, bh2, acc2, 0, 0, 0);
        acc2 = __builtin_amdgcn_mfma_f32_16x16x32_bf16(al, bh2, acc2, 0, 0, 0);
        acc2 = __builtin_amdgcn_mfma_f32_16x16x32_bf16(ah, bl2, acc2, 0, 0, 0);
    }

    // epilogue: D lane l reg r -> node mbase + 4*lg + r, class nt*16 + lr.
    int nlb = wid * 16 + 4 * lg;
    #pragma unroll
    for (int r = 0; r < 4; ++r) {
        int nd = mbase + 4 * lg + r;
        float di = (nd < n) ? dinv[nd] : 0.f;
        ep[(nlb + r) * EPS + 0 * 16 + lr] = acc0[r] * di;
        ep[(nlb + r) * EPS + 1 * 16 + lr] = acc1[r] * di;
        ep[(nlb + r) * EPS + 2 * 16 + lr] = acc2[r] * di;
    }
    __syncthreads();
    for (int i = t; i < 320; i += 256) {
        int nl2 = i / 5;
        int cg = i - nl2 * 5;
        int node = base64 + nl2;
        if (node < n) {
            const float* p = &ep[nl2 * EPS + cg * 8];
            float4 v0 = *(const float4*)p;
            float4 v1 = *(const float4*)(p + 4);
            uint4 o;
            o.x = pack2(v0.x, v0.y);
            o.y = pack2(v0.z, v0.w);
            o.z = pack2(v1.x, v1.y);
            o.w = pack2(v1.z, v1.w);
            Zbf[(size_t)node * ZSTR + cg] = o;
        }
    }
}

// ---- one hop: acc = sum_{s->i} Zin[s] + Zin[i]; Zout = di^2 * acc.
// FINAL: fuse logits = Z2*dsq + b and log_softmax, write fp32 d_out.
// 10 lanes/node = 2 teams x 5 c8-lanes; 8 edges/iter/team. Round-17:
// col loads software-pipelined (preload 8, prefetch next-8 between gather
// issue and accumulate) -- gathers of iter i+1 no longer wait on iter i's
// accumulate + fresh col loads. Guarded preload avoids deg-0 OOB.
template <bool FINAL>
__global__ __launch_bounds__(256) void prop_k(const int* __restrict__ rowptr,
                                              const int* __restrict__ col,
                                              const float* __restrict__ dinv,
                                              const float* __restrict__ dsq,
                                              const float* __restrict__ bias,
                                              const uint4* __restrict__ Zin,
                                              uint4* __restrict__ Zout_bf,
                                              float* __restrict__ out_f32, int n) {
    __shared__ float bsm[CDIM];
    __shared__ float red[256];
    __shared__ float pr[NPB * 5 * 8];   // team-1 partials, 4 KB
    int t = threadIdx.x;
    if (FINAL && t < CDIM) bsm[t] = bias[t];
    int g = t / 10;
    int r = t - g * 10;
    int team = r / 5;           // 0 or 1
    int c8 = r - team * 5;      // 0..4
    int node = blockIdx.x * NPB + g;
    bool active = (g < NPB) && (node < n);
    float acc[8];
    #pragma unroll
    for (int c = 0; c < 8; ++c) acc[c] = 0.f;
    float w = 0.f;
    if (active) {
        float di = dinv[node];
        w = di * di;
        if (team == 0) addu4(Zin[(size_t)node * ZSTR + c8], acc);   // self-loop
        int end = rowptr[node + 1];
        int end1 = end - 1;
        int e0 = rowptr[node] + team * 8;
        if (e0 < end) {
            int sv[8];
            #pragma unroll
            for (int k = 0; k < 8; ++k)
                sv[k] = col[min(e0 + k, end1)];     // preload iter 0
            for (int base = e0; base < end; base += 16) {
                uint4 av[8];
                #pragma unroll
                for (int k = 0; k < 8; ++k)
                    av[k] = Zin[(size_t)sv[k] * ZSTR + c8];  // 8 gathers in flight
                #pragma unroll
                for (int k = 0; k < 8; ++k)
                    sv[k] = col[min(base + 16 + k, end1)];   // prefetch iter+1
                #pragma unroll
                for (int k = 0; k < 8; ++k) {
                    if (base + k >= end) av[k] = make_uint4(0u, 0u, 0u, 0u);
                    addu4(av[k], acc);
                }
            }
        }
    }

    // merge team-1 partials into team-0 accumulators.
    if (active && team == 1) {
        float* p = &pr[(g * 5 + c8) * 8];
        #pragma unroll
        for (int j = 0; j < 8; ++j) p[j] = acc[j];
    }
    __syncthreads();   // also publishes bsm for FINAL
    if (active && team == 0) {
        const float* p = &pr[(g * 5 + c8) * 8];
        #pragma unroll
        for (int j = 0; j < 8; ++j) acc[j] += p[j];
    }

    if (!FINAL) {
        if (active && team == 0) {
            uint4 o;
            o.x = pack2(acc[0] * w, acc[1] * w);
            o.y = pack2(acc[2] * w, acc[3] * w);
            o.z = pack2(acc[4] * w, acc[5] * w);
            o.w = pack2(acc[6] * w, acc[7] * w);
            Zout_bf[(size_t)node * ZSTR + c8] = o;
        }
        return;
    }

    // FINAL: logits + log_softmax; reduce over the 5 team-0 lanes/node.
    float v[8];
    float m8 = -INFINITY;
    if (active && team == 0) {
        float ws_ = w * dsq[node];
        #pragma unroll
        for (int j = 0; j < 8; ++j) {
            v[j] = acc[j] * ws_ + bsm[c8 * 8 + j];
            m8 = fmaxf(m8, v[j]);
        }
    }
    red[t] = m8;
    __syncthreads();
    float m = m8;
    if (active && team == 0) {
        int rb = g * 10;
        m = fmaxf(fmaxf(fmaxf(red[rb], red[rb + 1]), fmaxf(red[rb + 2], red[rb + 3])),
                  red[rb + 4]);
    }
    float s8 = 0.f;
    if (active && team == 0) {
        #pragma unroll
        for (int j = 0; j < 8; ++j) s8 += expf(v[j] - m);
    }
    __syncthreads();
    red[t] = s8;
    __syncthreads();
    if (active && team == 0) {
        int rb = g * 10;
        float s = (red[rb] + red[rb + 1]) + (red[rb + 2] + red[rb + 3]) + red[rb + 4];
        float ls = m + logf(s);
        float* p = out_f32 + (size_t)node * CDIM + c8 * 8;
        *(float4*)p = make_float4(v[0] - ls, v[1] - ls, v[2] - ls, v[3] - ls);
        *(float4*)(p + 4) = make_float4(v[4] - ls, v[5] - ls, v[6] - ls, v[7] - ls);
    }
}

extern "C" void kernel_launch(void* const* d_in, const int* in_sizes, int n_in,
                              void* d_out, int out_size, void* d_ws, size_t ws_size,
                              hipStream_t stream) {
    const float* x = (const float*)d_in[0];
    const float* W = (const float*)d_in[1];
    const float* b = (const float*)d_in[2];
    const int* ei = (const int*)d_in[3];

    int C = in_sizes[2];            // 40
    int F = in_sizes[1] / C;        // 128
    int N = in_sizes[0] / F;        // 100000
    int E = in_sizes[3] / 2;        // 1600000
    const int* src = ei;
    const int* dst = ei + E;

    // workspace: union region holds {G,T,tmp} during build, then Z0bf
    // (12.8MB, 128B rows). Zb separate (hop-2 gathers from it while writing
    // d_out). WF separate (written by hist_k block NBLK, read by gemm_k).
    char* ws = (char*)d_ws;
    size_t goff = 0;
    int* G = (int*)(ws + goff);                       goff += (size_t)NBLK * NB * 4;
    int* T = (int*)(ws + goff);                       goff += (size_t)NB * 4;
    goff = (goff + 15) & ~(size_t)15;
    unsigned int* tmp = (unsigned int*)(ws + goff);   goff += (size_t)E * 4;
    size_t z0bytes = (size_t)N * ZSTR * 16;           // 128 B per node
    size_t unionEnd = (z0bytes > goff) ? z0bytes : goff;
    unionEnd = (unionEnd + 15) & ~(size_t)15;
    uint4* Z0bf = (uint4*)ws;        // overlays build scratch
    size_t off = unionEnd;
    int* rowptr = (int*)(ws + off); off += ((size_t)(N + 1) * 4 + 15) & ~(size_t)15;
    float* dinv = (float*)(ws + off); off += ((size_t)N * 4 + 15) & ~(size_t)15;
    float* dsq = (float*)(ws + off); off += ((size_t)N * 4 + 15) & ~(size_t)15;
    int* col = (int*)(ws + off); off += ((size_t)E * 4 + 15) & ~(size_t)15;
    uint4* Zb = (uint4*)(ws + off); off += (z0bytes + 15) & ~(size_t)15;
    uint4* WF = (uint4*)(ws + off); off += (size_t)2 * 768 * 16;

    // T is consumed by part_k and csr_k, both before gemm_k overwrites the
    // union region with Z0bf. Safe.

    int EB = (E + NBLK - 1) / NBLK;
    int NBr = (N + 255) >> BKT_SHIFT;

    hist_k<<<NBLK + 1, 256, 0, stream>>>(dst, G, E, EB, W, WF);
    colscan_k<<<NB, 256, 0, stream>>>(G, T);
    part_k<<<NBLK, 256, 0, stream>>>(src, dst, G, T, tmp, E, EB);
    csr_k<<<NBr, 256, 0, stream>>>(tmp, T, rowptr, dinv, dsq, col, N, E);

    gemm_k<<<(N + 63) / 64, 256, 0, stream>>>(x, WF, dinv, Z0bf, N);

    int pgrid = (N + NPB - 1) / NPB;
    prop_k<false><<<pgrid, 256, 0, stream>>>(rowptr, col, dinv, dsq, b,
                                             Z0bf, Zb, nullptr, N);
    prop_k<true><<<pgrid, 256, 0, stream>>>(rowptr, col, dinv, dsq, b,
                                            Zb, nullptr, (float*)d_out, N);
}